// Round 1
// baseline (4736.536 us; speedup 1.0000x reference)
//
#include <hip/hip_runtime.h>

#define Hd 256
#define Wd 256
#define HW 65536
#define C 64
#define B 8
#define M 16
#define NDEPTH 4
#define NMLP 128

// ---------------- twiddle table: e^{2*pi*i*t/256}, double-precision accurate --------------
__global__ void k_table(float2* __restrict__ tab) {
    int t = threadIdx.x;
    double a = (6.283185307179586476925286766559 / 256.0) * (double)t;
    tab[t] = make_float2((float)cos(a), (float)sin(a));
}

// ---------------- fc0: 3 -> 64 channels, per pixel ----------------
__global__ void k_fc0(const float* __restrict__ x, const float* __restrict__ w,
                      const float* __restrict__ bias, float* __restrict__ h) {
    int p = blockIdx.x * 256 + threadIdx.x;   // 0 .. B*HW-1
    int b = p >> 16, pix = p & 65535;
    float x0 = x[(b * 3 + 0) * HW + pix];
    float x1 = x[(b * 3 + 1) * HW + pix];
    float x2 = x[(b * 3 + 2) * HW + pix];
    for (int o = 0; o < C; ++o) {
        float v = bias[o];
        v = fmaf(w[o * 3 + 0], x0, v);
        v = fmaf(w[o * 3 + 1], x1, v);
        v = fmaf(w[o * 3 + 2], x2, v);
        h[(b * C + o) * HW + pix] = v;
    }
}

// ---------------- forward DFT along y: T1[bc,ky,w] = sum_y h[bc,y,w] e^{-2pi i ky y/256} ---
__global__ void k_fwd_y(const float* __restrict__ h, const float2* __restrict__ tab,
                        float2* __restrict__ T1) {
    int bc = blockIdx.x;          // b*C+c
    int w = threadIdx.x;          // 0..255
    const float* hp = h + bc * HW + w;
    float ar[M], ai[M];
#pragma unroll
    for (int k = 0; k < M; ++k) { ar[k] = 0.f; ai[k] = 0.f; }
    for (int y = 0; y < Hd; ++y) {
        float v = hp[y * Wd];
#pragma unroll
        for (int k = 0; k < M; ++k) {
            float2 e = tab[(k * y) & 255];   // uniform -> scalar load
            ar[k] = fmaf(v, e.x, ar[k]);
            ai[k] = fmaf(v, -e.y, ai[k]);
        }
    }
    float2* out = T1 + bc * (M * Wd) + w;
#pragma unroll
    for (int k = 0; k < M; ++k) out[k * Wd] = make_float2(ar[k], ai[k]);
}

// ---------------- forward DFT along x: X[bc, ky*16+kx] = sum_w T1[bc,ky,w] e^{-2pi i kx w/256}
__global__ void k_fwd_x(const float2* __restrict__ T1, const float2* __restrict__ tab,
                        float2* __restrict__ X) {
    __shared__ float2 sT[M * Wd];   // 32 KB
    __shared__ float2 st[256];      // 2 KB
    int bc = blockIdx.x, t = threadIdx.x;
    const float2* src = T1 + bc * (M * Wd);
#pragma unroll
    for (int j = 0; j < M; ++j) sT[j * 256 + t] = src[j * 256 + t];
    st[t] = tab[t];
    __syncthreads();
    int ky = t >> 4, kx = t & 15;
    float xr = 0.f, xi = 0.f;
    for (int w = 0; w < Wd; ++w) {
        float2 T = sT[ky * 256 + w];
        float2 e = st[(kx * w) & 255];
        xr = fmaf(T.x, e.x, fmaf(T.y, e.y, xr));
        xi = fmaf(T.y, e.x, fmaf(-T.x, e.y, xi));
    }
    X[bc * 256 + t] = make_float2(xr, xi);
}

// ---------------- mode mixing: Y[b,o,m] = sum_i X[b,i,m] * (wre+j*wim)[i,o,m] -------------
__global__ void k_mix(const float2* __restrict__ X, const float* __restrict__ wre,
                      const float* __restrict__ wim, float2* __restrict__ Y) {
    int o = blockIdx.x >> 2;   // 0..63
    int bq = blockIdx.x & 3;   // pair of batches
    int m = threadIdx.x;       // mode = ky*16+kx
    int b0 = bq * 2, b1 = bq * 2 + 1;
    float yr0 = 0.f, yi0 = 0.f, yr1 = 0.f, yi1 = 0.f;
    for (int i = 0; i < C; ++i) {
        float wr = wre[(i * C + o) * 256 + m];
        float wi = wim[(i * C + o) * 256 + m];
        float2 x0 = X[(b0 * C + i) * 256 + m];
        float2 x1 = X[(b1 * C + i) * 256 + m];
        yr0 = fmaf(x0.x, wr, fmaf(-x0.y, wi, yr0));
        yi0 = fmaf(x0.x, wi, fmaf(x0.y, wr, yi0));
        yr1 = fmaf(x1.x, wr, fmaf(-x1.y, wi, yr1));
        yi1 = fmaf(x1.x, wi, fmaf(x1.y, wr, yi1));
    }
    Y[(b0 * C + o) * 256 + m] = make_float2(yr0, yi0);
    Y[(b1 * C + o) * 256 + m] = make_float2(yr1, yi1);
}

// ---------------- inverse along y (with 1/(H*W) and Hermitian x2 folded in) ---------------
// G[bc, y, kx] = scale(kx) * sum_ky Y[bc, ky*16+kx] e^{+2pi i ky y/256}
__global__ void k_inv_y(const float2* __restrict__ Y, const float2* __restrict__ tab,
                        float2* __restrict__ G) {
    __shared__ float2 sY[256];
    __shared__ float2 st[256];
    int bc = blockIdx.x, t = threadIdx.x;   // t = y
    sY[t] = Y[bc * 256 + t];
    st[t] = tab[t];
    __syncthreads();
    float2 out[M];
#pragma unroll
    for (int kx = 0; kx < M; ++kx) {
        float gr = 0.f, gi = 0.f;
#pragma unroll
        for (int ky = 0; ky < M; ++ky) {
            float2 yv = sY[ky * 16 + kx];
            float2 e = st[(ky * t) & 255];
            gr = fmaf(yv.x, e.x, fmaf(-yv.y, e.y, gr));
            gi = fmaf(yv.x, e.y, fmaf(yv.y, e.x, gi));
        }
        float sc = (kx == 0 ? 1.0f : 2.0f) * (1.0f / 65536.0f);
        out[kx] = make_float2(gr * sc, gi * sc);
    }
    float2* gp = G + (bc * 256 + t) * M;
#pragma unroll
    for (int kx = 0; kx < M; ++kx) gp[kx] = out[kx];
}

// ---------------- fused: inverse along x + conv1x1 + add + relu, in-place on h ------------
__global__ void k_final(float* __restrict__ h, const float2* __restrict__ G,
                        const float* __restrict__ ww, const float* __restrict__ wb,
                        const float2* __restrict__ tab) {
    __shared__ float2 st[256];
    int by = blockIdx.x;
    int b = by >> 8, y = by & 255;
    int x = threadIdx.x;
    st[x] = tab[x];
    __syncthreads();
    float cs[M], sn[M];
#pragma unroll
    for (int k = 0; k < M; ++k) {
        float2 e = st[(k * x) & 255];
        cs[k] = e.x; sn[k] = e.y;
    }
    float hp[C];
    float* hb = h + b * C * HW + y * Wd + x;
#pragma unroll
    for (int i = 0; i < C; ++i) hp[i] = hb[i * HW];
    for (int o = 0; o < C; ++o) {
        const float* wr = ww + o * C;        // uniform -> scalar loads
        float acc = wb[o];
#pragma unroll
        for (int i = 0; i < C; ++i) acc = fmaf(wr[i], hp[i], acc);
        const float2* gp = G + ((b * C + o) * 256 + y) * M;   // uniform -> scalar loads
#pragma unroll
        for (int k = 0; k < M; ++k) {
            float2 g = gp[k];
            acc = fmaf(g.x, cs[k], fmaf(-g.y, sn[k], acc));
        }
        hb[o * HW] = fmaxf(acc, 0.0f);
    }
}

// ---------------- fused fc1 (relu) + fc2, per pixel ----------------
__global__ void k_fc12(const float* __restrict__ h, const float* __restrict__ w1,
                       const float* __restrict__ b1, const float* __restrict__ w2,
                       const float* __restrict__ b2, float* __restrict__ out) {
    int by = blockIdx.x;
    int b = by >> 8, y = by & 255;
    int x = threadIdx.x;
    const float* hb = h + b * C * HW + y * Wd + x;
    float hp[C];
#pragma unroll
    for (int i = 0; i < C; ++i) hp[i] = hb[i * HW];
    float a0 = b2[0], a1 = b2[1], a2 = b2[2];
    for (int m = 0; m < NMLP; ++m) {
        const float* wr = w1 + m * C;
        float acc = b1[m];
#pragma unroll
        for (int i = 0; i < C; ++i) acc = fmaf(wr[i], hp[i], acc);
        acc = fmaxf(acc, 0.0f);
        a0 = fmaf(w2[0 * NMLP + m], acc, a0);
        a1 = fmaf(w2[1 * NMLP + m], acc, a1);
        a2 = fmaf(w2[2 * NMLP + m], acc, a2);
    }
    float* ob = out + b * 3 * HW + y * Wd + x;
    ob[0] = a0;
    ob[HW] = a1;
    ob[2 * HW] = a2;
}

extern "C" void kernel_launch(void* const* d_in, const int* in_sizes, int n_in,
                              void* d_out, int out_size, void* d_ws, size_t ws_size,
                              hipStream_t stream) {
    const float* x     = (const float*)d_in[0];
    const float* fc0_w = (const float*)d_in[1];
    const float* fc0_b = (const float*)d_in[2];
    const float* swre  = (const float*)d_in[3];   // [4,64,64,16,16]
    const float* swim  = (const float*)d_in[4];
    const float* ww    = (const float*)d_in[5];   // [4,64,64]
    const float* wb    = (const float*)d_in[6];   // [4,64]
    const float* fc1w  = (const float*)d_in[7];
    const float* fc1b  = (const float*)d_in[8];
    const float* fc2w  = (const float*)d_in[9];
    const float* fc2b  = (const float*)d_in[10];

    float* ws = (float*)d_ws;
    float2* tab = (float2*)ws;                               // 512 floats
    float*  h   = ws + 512;                                  // 33,554,432 floats
    float2* T1  = (float2*)(ws + 512 + 33554432);            // 4,194,304 floats (doubles as G)
    float2* X   = (float2*)(ws + 512 + 33554432 + 4194304);  // 262,144 floats
    float2* Y   = (float2*)(ws + 512 + 33554432 + 4194304 + 262144); // 262,144 floats
    // total ~153 MB of workspace

    k_table<<<dim3(1), dim3(256), 0, stream>>>(tab);
    k_fc0<<<dim3(2048), dim3(256), 0, stream>>>(x, fc0_w, fc0_b, h);

    for (int d = 0; d < NDEPTH; ++d) {
        k_fwd_y<<<dim3(512), dim3(256), 0, stream>>>(h, tab, T1);
        k_fwd_x<<<dim3(512), dim3(256), 0, stream>>>(T1, tab, X);
        k_mix<<<dim3(256), dim3(256), 0, stream>>>(X, swre + (size_t)d * C * C * 256,
                                                   swim + (size_t)d * C * C * 256, Y);
        k_inv_y<<<dim3(512), dim3(256), 0, stream>>>(Y, tab, T1 /* reused as G */);
        k_final<<<dim3(2048), dim3(256), 0, stream>>>(h, T1, ww + d * C * C, wb + d * C, tab);
    }
    k_fc12<<<dim3(2048), dim3(256), 0, stream>>>(h, fc1w, fc1b, fc2w, fc2b, (float*)d_out);
}

// Round 2
// 1732.351 us; speedup vs baseline: 2.7342x; 2.7342x over previous
//
#include <hip/hip_runtime.h>

#define Hd 256
#define Wd 256
#define HW 65536
#define C 64
#define B 8
#define M 16
#define NDEPTH 4
#define NMLP 128

// ---------------- twiddle table: e^{2*pi*i*t/256}, double-precision accurate --------------
__global__ void k_table(float2* __restrict__ tab) {
    int t = threadIdx.x;
    double a = (6.283185307179586476925286766559 / 256.0) * (double)t;
    tab[t] = make_float2((float)cos(a), (float)sin(a));
}

// ---------------- fc0: 3 -> 64 channels, per pixel ----------------
__global__ void k_fc0(const float* __restrict__ x, const float* __restrict__ w,
                      const float* __restrict__ bias, float* __restrict__ h) {
    int p = blockIdx.x * 256 + threadIdx.x;   // 0 .. B*HW-1
    int b = p >> 16, pix = p & 65535;
    float x0 = x[(b * 3 + 0) * HW + pix];
    float x1 = x[(b * 3 + 1) * HW + pix];
    float x2 = x[(b * 3 + 2) * HW + pix];
    for (int o = 0; o < C; ++o) {
        float v = bias[o];
        v = fmaf(w[o * 3 + 0], x0, v);
        v = fmaf(w[o * 3 + 1], x1, v);
        v = fmaf(w[o * 3 + 2], x2, v);
        h[(b * C + o) * HW + pix] = v;
    }
}

// ---------------- forward DFT along y: T1[bc,ky,w] = sum_y h[bc,y,w] e^{-2pi i ky y/256} ---
__global__ __launch_bounds__(256, 2)
void k_fwd_y(const float* __restrict__ h, const float2* __restrict__ tab,
             float2* __restrict__ T1) {
    int bc = blockIdx.x;          // b*C+c
    int w = threadIdx.x;          // 0..255
    const float* hp = h + bc * HW + w;
    float ar[M], ai[M];
#pragma unroll
    for (int k = 0; k < M; ++k) { ar[k] = 0.f; ai[k] = 0.f; }
    for (int y = 0; y < Hd; ++y) {
        float v = hp[y * Wd];
#pragma unroll
        for (int k = 0; k < M; ++k) {
            float2 e = tab[(k * y) & 255];   // uniform -> scalar load
            ar[k] = fmaf(v, e.x, ar[k]);
            ai[k] = fmaf(v, -e.y, ai[k]);
        }
    }
    float2* out = T1 + bc * (M * Wd) + w;
#pragma unroll
    for (int k = 0; k < M; ++k) out[k * Wd] = make_float2(ar[k], ai[k]);
}

// ---------------- forward DFT along x: X[bc, ky*16+kx] = sum_w T1[bc,ky,w] e^{-2pi i kx w/256}
__global__ __launch_bounds__(256, 2)
void k_fwd_x(const float2* __restrict__ T1, const float2* __restrict__ tab,
             float2* __restrict__ X) {
    __shared__ float2 sT[M * Wd];   // 32 KB
    __shared__ float2 st[256];      // 2 KB
    int bc = blockIdx.x, t = threadIdx.x;
    const float2* src = T1 + bc * (M * Wd);
#pragma unroll
    for (int j = 0; j < M; ++j) sT[j * 256 + t] = src[j * 256 + t];
    st[t] = tab[t];
    __syncthreads();
    int ky = t >> 4, kx = t & 15;
    float xr = 0.f, xi = 0.f;
    for (int w = 0; w < Wd; ++w) {
        float2 T = sT[ky * 256 + w];
        float2 e = st[(kx * w) & 255];
        xr = fmaf(T.x, e.x, fmaf(T.y, e.y, xr));
        xi = fmaf(T.y, e.x, fmaf(-T.x, e.y, xi));
    }
    X[bc * 256 + t] = make_float2(xr, xi);
}

// ---------------- mode mixing: Y[b,o,m] = sum_i X[b,i,m] * (wre+j*wim)[i,o,m] -------------
__global__ __launch_bounds__(256, 2)
void k_mix(const float2* __restrict__ X, const float* __restrict__ wre,
           const float* __restrict__ wim, float2* __restrict__ Y) {
    int o = blockIdx.x >> 2;   // 0..63
    int bq = blockIdx.x & 3;   // pair of batches
    int m = threadIdx.x;       // mode = ky*16+kx
    int b0 = bq * 2, b1 = bq * 2 + 1;
    float yr0 = 0.f, yi0 = 0.f, yr1 = 0.f, yi1 = 0.f;
    for (int i = 0; i < C; ++i) {
        float wr = wre[(i * C + o) * 256 + m];
        float wi = wim[(i * C + o) * 256 + m];
        float2 x0 = X[(b0 * C + i) * 256 + m];
        float2 x1 = X[(b1 * C + i) * 256 + m];
        yr0 = fmaf(x0.x, wr, fmaf(-x0.y, wi, yr0));
        yi0 = fmaf(x0.x, wi, fmaf(x0.y, wr, yi0));
        yr1 = fmaf(x1.x, wr, fmaf(-x1.y, wi, yr1));
        yi1 = fmaf(x1.x, wi, fmaf(x1.y, wr, yi1));
    }
    Y[(b0 * C + o) * 256 + m] = make_float2(yr0, yi0);
    Y[(b1 * C + o) * 256 + m] = make_float2(yr1, yi1);
}

// ---------------- inverse along y (with 1/(H*W) and Hermitian x2 folded in) ---------------
// G[bc, y, kx] = scale(kx) * sum_ky Y[bc, ky*16+kx] e^{+2pi i ky y/256}
__global__ __launch_bounds__(256, 2)
void k_inv_y(const float2* __restrict__ Y, const float2* __restrict__ tab,
             float2* __restrict__ G) {
    __shared__ float2 sY[256];
    __shared__ float2 st[256];
    int bc = blockIdx.x, t = threadIdx.x;   // t = y
    sY[t] = Y[bc * 256 + t];
    st[t] = tab[t];
    __syncthreads();
    float2 out[M];
#pragma unroll
    for (int kx = 0; kx < M; ++kx) {
        float gr = 0.f, gi = 0.f;
#pragma unroll
        for (int ky = 0; ky < M; ++ky) {
            float2 yv = sY[ky * 16 + kx];
            float2 e = st[(ky * t) & 255];
            gr = fmaf(yv.x, e.x, fmaf(-yv.y, e.y, gr));
            gi = fmaf(yv.x, e.y, fmaf(yv.y, e.x, gi));
        }
        float sc = (kx == 0 ? 1.0f : 2.0f) * (1.0f / 65536.0f);
        out[kx] = make_float2(gr * sc, gi * sc);
    }
    float2* gp = G + (bc * 256 + t) * M;
#pragma unroll
    for (int kx = 0; kx < M; ++kx) gp[kx] = out[kx];
}

// ---------------- fused: inverse along x + conv1x1 + add + relu, in-place on h ------------
// __launch_bounds__(256,2): default heuristic capped VGPRs at 64 and spilled hp[64]
// to scratch (R1: FETCH_SIZE 2.5 GB vs 0.35 GB ideal). 2 waves/EU -> 256 VGPR cap.
__global__ __launch_bounds__(256, 2)
void k_final(float* __restrict__ h, const float2* __restrict__ G,
             const float* __restrict__ ww, const float* __restrict__ wb,
             const float2* __restrict__ tab) {
    __shared__ float2 st[256];
    int by = blockIdx.x;
    int b = by >> 8, y = by & 255;
    int x = threadIdx.x;
    st[x] = tab[x];
    __syncthreads();
    float cs[M], sn[M];
#pragma unroll
    for (int k = 0; k < M; ++k) {
        float2 e = st[(k * x) & 255];
        cs[k] = e.x; sn[k] = e.y;
    }
    float hp[C];
    float* hb = h + b * C * HW + y * Wd + x;
#pragma unroll
    for (int i = 0; i < C; ++i) hp[i] = hb[i * HW];
    for (int o = 0; o < C; ++o) {
        const float* wr = ww + o * C;        // uniform -> scalar loads
        float acc = wb[o];
#pragma unroll
        for (int i = 0; i < C; ++i) acc = fmaf(wr[i], hp[i], acc);
        const float2* gp = G + ((b * C + o) * 256 + y) * M;   // uniform -> scalar loads
#pragma unroll
        for (int k = 0; k < M; ++k) {
            float2 g = gp[k];
            acc = fmaf(g.x, cs[k], fmaf(-g.y, sn[k], acc));
        }
        hb[o * HW] = fmaxf(acc, 0.0f);
    }
}

// ---------------- fused fc1 (relu) + fc2, per pixel ----------------
__global__ __launch_bounds__(256, 2)
void k_fc12(const float* __restrict__ h, const float* __restrict__ w1,
            const float* __restrict__ b1, const float* __restrict__ w2,
            const float* __restrict__ b2, float* __restrict__ out) {
    int by = blockIdx.x;
    int b = by >> 8, y = by & 255;
    int x = threadIdx.x;
    const float* hb = h + b * C * HW + y * Wd + x;
    float hp[C];
#pragma unroll
    for (int i = 0; i < C; ++i) hp[i] = hb[i * HW];
    float a0 = b2[0], a1 = b2[1], a2 = b2[2];
    for (int m = 0; m < NMLP; ++m) {
        const float* wr = w1 + m * C;
        float acc = b1[m];
#pragma unroll
        for (int i = 0; i < C; ++i) acc = fmaf(wr[i], hp[i], acc);
        acc = fmaxf(acc, 0.0f);
        a0 = fmaf(w2[0 * NMLP + m], acc, a0);
        a1 = fmaf(w2[1 * NMLP + m], acc, a1);
        a2 = fmaf(w2[2 * NMLP + m], acc, a2);
    }
    float* ob = out + b * 3 * HW + y * Wd + x;
    ob[0] = a0;
    ob[HW] = a1;
    ob[2 * HW] = a2;
}

extern "C" void kernel_launch(void* const* d_in, const int* in_sizes, int n_in,
                              void* d_out, int out_size, void* d_ws, size_t ws_size,
                              hipStream_t stream) {
    const float* x     = (const float*)d_in[0];
    const float* fc0_w = (const float*)d_in[1];
    const float* fc0_b = (const float*)d_in[2];
    const float* swre  = (const float*)d_in[3];   // [4,64,64,16,16]
    const float* swim  = (const float*)d_in[4];
    const float* ww    = (const float*)d_in[5];   // [4,64,64]
    const float* wb    = (const float*)d_in[6];   // [4,64]
    const float* fc1w  = (const float*)d_in[7];
    const float* fc1b  = (const float*)d_in[8];
    const float* fc2w  = (const float*)d_in[9];
    const float* fc2b  = (const float*)d_in[10];

    float* ws = (float*)d_ws;
    float2* tab = (float2*)ws;                               // 512 floats
    float*  h   = ws + 512;                                  // 33,554,432 floats
    float2* T1  = (float2*)(ws + 512 + 33554432);            // 4,194,304 floats (doubles as G)
    float2* X   = (float2*)(ws + 512 + 33554432 + 4194304);  // 262,144 floats
    float2* Y   = (float2*)(ws + 512 + 33554432 + 4194304 + 262144); // 262,144 floats
    // total ~153 MB of workspace

    k_table<<<dim3(1), dim3(256), 0, stream>>>(tab);
    k_fc0<<<dim3(2048), dim3(256), 0, stream>>>(x, fc0_w, fc0_b, h);

    for (int d = 0; d < NDEPTH; ++d) {
        k_fwd_y<<<dim3(512), dim3(256), 0, stream>>>(h, tab, T1);
        k_fwd_x<<<dim3(512), dim3(256), 0, stream>>>(T1, tab, X);
        k_mix<<<dim3(256), dim3(256), 0, stream>>>(X, swre + (size_t)d * C * C * 256,
                                                   swim + (size_t)d * C * C * 256, Y);
        k_inv_y<<<dim3(512), dim3(256), 0, stream>>>(Y, tab, T1 /* reused as G */);
        k_final<<<dim3(2048), dim3(256), 0, stream>>>(h, T1, ww + d * C * C, wb + d * C, tab);
    }
    k_fc12<<<dim3(2048), dim3(256), 0, stream>>>(h, fc1w, fc1b, fc2w, fc2b, (float*)d_out);
}

// Round 3
// 1463.048 us; speedup vs baseline: 3.2374x; 1.1841x over previous
//
#include <hip/hip_runtime.h>

#define Hd 256
#define Wd 256
#define HW 65536
#define C 64
#define B 8
#define M 16
#define NDEPTH 4
#define NMLP 128

// ---------------- twiddle table: e^{2*pi*i*t/256}, double-precision accurate --------------
__global__ void k_table(float2* __restrict__ tab) {
    int t = threadIdx.x;
    double a = (6.283185307179586476925286766559 / 256.0) * (double)t;
    tab[t] = make_float2((float)cos(a), (float)sin(a));
}

// ---------------- fc0: 3 -> 64 channels, per pixel ----------------
__global__ void k_fc0(const float* __restrict__ x, const float* __restrict__ w,
                      const float* __restrict__ bias, float* __restrict__ h) {
    int p = blockIdx.x * 256 + threadIdx.x;   // 0 .. B*HW-1
    int b = p >> 16, pix = p & 65535;
    float x0 = x[(b * 3 + 0) * HW + pix];
    float x1 = x[(b * 3 + 1) * HW + pix];
    float x2 = x[(b * 3 + 2) * HW + pix];
    for (int o = 0; o < C; ++o) {
        float v = bias[o];
        v = fmaf(w[o * 3 + 0], x0, v);
        v = fmaf(w[o * 3 + 1], x1, v);
        v = fmaf(w[o * 3 + 2], x2, v);
        h[(b * C + o) * HW + pix] = v;
    }
}

// ---------------- forward DFT along y: T1[bc,ky,w] = sum_y h[bc,y,w] e^{-2pi i ky y/256} ---
__global__ __launch_bounds__(256, 2)
void k_fwd_y(const float* __restrict__ h, const float2* __restrict__ tab,
             float2* __restrict__ T1) {
    int bc = blockIdx.x;          // b*C+c
    int w = threadIdx.x;          // 0..255
    const float* hp = h + bc * HW + w;
    float ar[M], ai[M];
#pragma unroll
    for (int k = 0; k < M; ++k) { ar[k] = 0.f; ai[k] = 0.f; }
    for (int y = 0; y < Hd; ++y) {
        float v = hp[y * Wd];
#pragma unroll
        for (int k = 0; k < M; ++k) {
            float2 e = tab[(k * y) & 255];   // uniform -> scalar load
            ar[k] = fmaf(v, e.x, ar[k]);
            ai[k] = fmaf(v, -e.y, ai[k]);
        }
    }
    float2* out = T1 + bc * (M * Wd) + w;
#pragma unroll
    for (int k = 0; k < M; ++k) out[k * Wd] = make_float2(ar[k], ai[k]);
}

// ---------------- forward DFT along x: X[bc, ky*16+kx] = sum_w T1[bc,ky,w] e^{-2pi i kx w/256}
__global__ __launch_bounds__(256, 2)
void k_fwd_x(const float2* __restrict__ T1, const float2* __restrict__ tab,
             float2* __restrict__ X) {
    __shared__ float2 sT[M * Wd];   // 32 KB
    __shared__ float2 st[256];      // 2 KB
    int bc = blockIdx.x, t = threadIdx.x;
    const float2* src = T1 + bc * (M * Wd);
#pragma unroll
    for (int j = 0; j < M; ++j) sT[j * 256 + t] = src[j * 256 + t];
    st[t] = tab[t];
    __syncthreads();
    int ky = t >> 4, kx = t & 15;
    float xr = 0.f, xi = 0.f;
    for (int w = 0; w < Wd; ++w) {
        float2 T = sT[ky * 256 + w];
        float2 e = st[(kx * w) & 255];
        xr = fmaf(T.x, e.x, fmaf(T.y, e.y, xr));
        xi = fmaf(T.y, e.x, fmaf(-T.x, e.y, xi));
    }
    X[bc * 256 + t] = make_float2(xr, xi);
}

// ---------------- mode mixing: Y[b,o,m] = sum_i X[b,i,m] * (wre+j*wim)[i,o,m] -------------
__global__ __launch_bounds__(256, 2)
void k_mix(const float2* __restrict__ X, const float* __restrict__ wre,
           const float* __restrict__ wim, float2* __restrict__ Y) {
    int o = blockIdx.x >> 2;   // 0..63
    int bq = blockIdx.x & 3;   // pair of batches
    int m = threadIdx.x;       // mode = ky*16+kx
    int b0 = bq * 2, b1 = bq * 2 + 1;
    float yr0 = 0.f, yi0 = 0.f, yr1 = 0.f, yi1 = 0.f;
    for (int i = 0; i < C; ++i) {
        float wr = wre[(i * C + o) * 256 + m];
        float wi = wim[(i * C + o) * 256 + m];
        float2 x0 = X[(b0 * C + i) * 256 + m];
        float2 x1 = X[(b1 * C + i) * 256 + m];
        yr0 = fmaf(x0.x, wr, fmaf(-x0.y, wi, yr0));
        yi0 = fmaf(x0.x, wi, fmaf(x0.y, wr, yi0));
        yr1 = fmaf(x1.x, wr, fmaf(-x1.y, wi, yr1));
        yi1 = fmaf(x1.x, wi, fmaf(x1.y, wr, yi1));
    }
    Y[(b0 * C + o) * 256 + m] = make_float2(yr0, yi0);
    Y[(b1 * C + o) * 256 + m] = make_float2(yr1, yi1);
}

// ---------------- inverse along y (with 1/(H*W) and Hermitian x2 folded in) ---------------
// G[bc, y, kx] = scale(kx) * sum_ky Y[bc, ky*16+kx] e^{+2pi i ky y/256}
__global__ __launch_bounds__(256, 2)
void k_inv_y(const float2* __restrict__ Y, const float2* __restrict__ tab,
             float2* __restrict__ G) {
    __shared__ float2 sY[256];
    __shared__ float2 st[256];
    int bc = blockIdx.x, t = threadIdx.x;   // t = y
    sY[t] = Y[bc * 256 + t];
    st[t] = tab[t];
    __syncthreads();
    float2 out[M];
#pragma unroll
    for (int kx = 0; kx < M; ++kx) {
        float gr = 0.f, gi = 0.f;
#pragma unroll
        for (int ky = 0; ky < M; ++ky) {
            float2 yv = sY[ky * 16 + kx];
            float2 e = st[(ky * t) & 255];
            gr = fmaf(yv.x, e.x, fmaf(-yv.y, e.y, gr));
            gi = fmaf(yv.x, e.y, fmaf(yv.y, e.x, gi));
        }
        float sc = (kx == 0 ? 1.0f : 2.0f) * (1.0f / 65536.0f);
        out[kx] = make_float2(gr * sc, gi * sc);
    }
    float2* gp = G + (bc * 256 + t) * M;
#pragma unroll
    for (int kx = 0; kx < M; ++kx) gp[kx] = out[kx];
}

// ---------------- fused: inverse along x + conv1x1 + add + relu, in-place on h ------------
// __launch_bounds__(256,2): default heuristic capped VGPRs at 64 and spilled hp[64] (R1).
// R3: stage this block's G slice (64 o x 16 k float2 = 8 KB) in LDS via coalesced float4
// loads. R2 showed per-o wave-uniform G loads became scalar loads that miss sL1 every
// iteration (G footprint 32 MB, unique per block) -> ~200 cyc serialized stall per o.
// LDS broadcast reads overlap with the FMA pipe instead.
__global__ __launch_bounds__(256, 2)
void k_final(float* __restrict__ h, const float2* __restrict__ G,
             const float* __restrict__ ww, const float* __restrict__ wb,
             const float2* __restrict__ tab) {
    __shared__ float2 sG[C * M];    // 8 KB, [o][k]
    __shared__ float2 st[256];      // 2 KB
    int by = blockIdx.x;
    int b = by >> 8, y = by & 255;
    int x = threadIdx.x;
    st[x] = tab[x];
    {
        // 64 o-rows x 8 float4 each = 512 float4; threads f=8o..8o+7 fetch one
        // contiguous 128 B row -> fully coalesced.
        const float4* Gf4 = (const float4*)G;
        float4* sGf4 = (float4*)sG;
        int f0 = x;                      // pass 0
        int o0 = f0 >> 3, q0 = f0 & 7;
        sGf4[f0] = Gf4[((size_t)(b * C + o0) * 256 + y) * 8 + q0];
        int f1 = x + 256;                // pass 1
        int o1 = f1 >> 3, q1 = f1 & 7;
        sGf4[f1] = Gf4[((size_t)(b * C + o1) * 256 + y) * 8 + q1];
    }
    __syncthreads();
    float cs[M], sn[M];
#pragma unroll
    for (int k = 0; k < M; ++k) {
        float2 e = st[(k * x) & 255];
        cs[k] = e.x; sn[k] = e.y;
    }
    float hp[C];
    float* hb = h + b * C * HW + y * Wd + x;
#pragma unroll
    for (int i = 0; i < C; ++i) hp[i] = hb[i * HW];
    for (int o = 0; o < C; ++o) {
        const float* wr = ww + o * C;        // uniform -> scalar loads (sL1-hot, shared by all blocks)
        float acc = wb[o];
#pragma unroll
        for (int i = 0; i < C; ++i) acc = fmaf(wr[i], hp[i], acc);
        const float2* gp = &sG[o * M];       // uniform LDS -> broadcast, conflict-free
#pragma unroll
        for (int k = 0; k < M; ++k) {
            float2 g = gp[k];
            acc = fmaf(g.x, cs[k], fmaf(-g.y, sn[k], acc));
        }
        hb[o * HW] = fmaxf(acc, 0.0f);
    }
}

// ---------------- fused fc1 (relu) + fc2, per pixel ----------------
__global__ __launch_bounds__(256, 2)
void k_fc12(const float* __restrict__ h, const float* __restrict__ w1,
            const float* __restrict__ b1, const float* __restrict__ w2,
            const float* __restrict__ b2, float* __restrict__ out) {
    int by = blockIdx.x;
    int b = by >> 8, y = by & 255;
    int x = threadIdx.x;
    const float* hb = h + b * C * HW + y * Wd + x;
    float hp[C];
#pragma unroll
    for (int i = 0; i < C; ++i) hp[i] = hb[i * HW];
    float a0 = b2[0], a1 = b2[1], a2 = b2[2];
    for (int m = 0; m < NMLP; ++m) {
        const float* wr = w1 + m * C;
        float acc = b1[m];
#pragma unroll
        for (int i = 0; i < C; ++i) acc = fmaf(wr[i], hp[i], acc);
        acc = fmaxf(acc, 0.0f);
        a0 = fmaf(w2[0 * NMLP + m], acc, a0);
        a1 = fmaf(w2[1 * NMLP + m], acc, a1);
        a2 = fmaf(w2[2 * NMLP + m], acc, a2);
    }
    float* ob = out + b * 3 * HW + y * Wd + x;
    ob[0] = a0;
    ob[HW] = a1;
    ob[2 * HW] = a2;
}

extern "C" void kernel_launch(void* const* d_in, const int* in_sizes, int n_in,
                              void* d_out, int out_size, void* d_ws, size_t ws_size,
                              hipStream_t stream) {
    const float* x     = (const float*)d_in[0];
    const float* fc0_w = (const float*)d_in[1];
    const float* fc0_b = (const float*)d_in[2];
    const float* swre  = (const float*)d_in[3];   // [4,64,64,16,16]
    const float* swim  = (const float*)d_in[4];
    const float* ww    = (const float*)d_in[5];   // [4,64,64]
    const float* wb    = (const float*)d_in[6];   // [4,64]
    const float* fc1w  = (const float*)d_in[7];
    const float* fc1b  = (const float*)d_in[8];
    const float* fc2w  = (const float*)d_in[9];
    const float* fc2b  = (const float*)d_in[10];

    float* ws = (float*)d_ws;
    float2* tab = (float2*)ws;                               // 512 floats
    float*  h   = ws + 512;                                  // 33,554,432 floats
    float2* T1  = (float2*)(ws + 512 + 33554432);            // 4,194,304 floats (doubles as G)
    float2* X   = (float2*)(ws + 512 + 33554432 + 4194304);  // 262,144 floats
    float2* Y   = (float2*)(ws + 512 + 33554432 + 4194304 + 262144); // 262,144 floats
    // total ~153 MB of workspace

    k_table<<<dim3(1), dim3(256), 0, stream>>>(tab);
    k_fc0<<<dim3(2048), dim3(256), 0, stream>>>(x, fc0_w, fc0_b, h);

    for (int d = 0; d < NDEPTH; ++d) {
        k_fwd_y<<<dim3(512), dim3(256), 0, stream>>>(h, tab, T1);
        k_fwd_x<<<dim3(512), dim3(256), 0, stream>>>(T1, tab, X);
        k_mix<<<dim3(256), dim3(256), 0, stream>>>(X, swre + (size_t)d * C * C * 256,
                                                   swim + (size_t)d * C * C * 256, Y);
        k_inv_y<<<dim3(512), dim3(256), 0, stream>>>(Y, tab, T1 /* reused as G */);
        k_final<<<dim3(2048), dim3(256), 0, stream>>>(h, T1, ww + d * C * C, wb + d * C, tab);
    }
    k_fc12<<<dim3(2048), dim3(256), 0, stream>>>(h, fc1w, fc1b, fc2w, fc2b, (float*)d_out);
}

// Round 4
// 1454.160 us; speedup vs baseline: 3.2572x; 1.0061x over previous
//
#include <hip/hip_runtime.h>

#define Hd 256
#define Wd 256
#define HW 65536
#define C 64
#define B 8
#define M 16
#define NDEPTH 4
#define NMLP 128

// ---------------- twiddle table: e^{2*pi*i*t/256}, double-precision accurate --------------
__global__ void k_table(float2* __restrict__ tab) {
    int t = threadIdx.x;
    double a = (6.283185307179586476925286766559 / 256.0) * (double)t;
    tab[t] = make_float2((float)cos(a), (float)sin(a));
}

// ---------------- fc0: 3 -> 64 channels, per pixel ----------------
__global__ void k_fc0(const float* __restrict__ x, const float* __restrict__ w,
                      const float* __restrict__ bias, float* __restrict__ h) {
    int p = blockIdx.x * 256 + threadIdx.x;   // 0 .. B*HW-1
    int b = p >> 16, pix = p & 65535;
    float x0 = x[(b * 3 + 0) * HW + pix];
    float x1 = x[(b * 3 + 1) * HW + pix];
    float x2 = x[(b * 3 + 2) * HW + pix];
    for (int o = 0; o < C; ++o) {
        float v = bias[o];
        v = fmaf(w[o * 3 + 0], x0, v);
        v = fmaf(w[o * 3 + 1], x1, v);
        v = fmaf(w[o * 3 + 2], x2, v);
        h[(b * C + o) * HW + pix] = v;
    }
}

// ---------------- forward DFT along y: T1[bc,ky,w] = sum_y h[bc,y,w] e^{-2pi i ky y/256} ---
__global__ __launch_bounds__(256, 2)
void k_fwd_y(const float* __restrict__ h, const float2* __restrict__ tab,
             float2* __restrict__ T1) {
    int bc = blockIdx.x;          // b*C+c
    int w = threadIdx.x;          // 0..255
    const float* hp = h + bc * HW + w;
    float ar[M], ai[M];
#pragma unroll
    for (int k = 0; k < M; ++k) { ar[k] = 0.f; ai[k] = 0.f; }
    for (int y = 0; y < Hd; ++y) {
        float v = hp[y * Wd];
#pragma unroll
        for (int k = 0; k < M; ++k) {
            float2 e = tab[(k * y) & 255];   // uniform -> scalar load
            ar[k] = fmaf(v, e.x, ar[k]);
            ai[k] = fmaf(v, -e.y, ai[k]);
        }
    }
    float2* out = T1 + bc * (M * Wd) + w;
#pragma unroll
    for (int k = 0; k < M; ++k) out[k * Wd] = make_float2(ar[k], ai[k]);
}

// ---------------- forward DFT along x: X[bc, ky*16+kx] = sum_w T1[bc,ky,w] e^{-2pi i kx w/256}
__global__ __launch_bounds__(256, 2)
void k_fwd_x(const float2* __restrict__ T1, const float2* __restrict__ tab,
             float2* __restrict__ X) {
    __shared__ float2 sT[M * Wd];   // 32 KB
    __shared__ float2 st[256];      // 2 KB
    int bc = blockIdx.x, t = threadIdx.x;
    const float2* src = T1 + bc * (M * Wd);
#pragma unroll
    for (int j = 0; j < M; ++j) sT[j * 256 + t] = src[j * 256 + t];
    st[t] = tab[t];
    __syncthreads();
    int ky = t >> 4, kx = t & 15;
    // 2 independent chains (w even / w odd) to break the serial FMA dependency
    float xr0 = 0.f, xi0 = 0.f, xr1 = 0.f, xi1 = 0.f;
    for (int w = 0; w < Wd; w += 2) {
        float2 Ta = sT[ky * 256 + w];
        float2 ea = st[(kx * w) & 255];
        xr0 = fmaf(Ta.x, ea.x, fmaf(Ta.y, ea.y, xr0));
        xi0 = fmaf(Ta.y, ea.x, fmaf(-Ta.x, ea.y, xi0));
        float2 Tb = sT[ky * 256 + w + 1];
        float2 eb = st[(kx * (w + 1)) & 255];
        xr1 = fmaf(Tb.x, eb.x, fmaf(Tb.y, eb.y, xr1));
        xi1 = fmaf(Tb.y, eb.x, fmaf(-Tb.x, eb.y, xi1));
    }
    X[bc * 256 + t] = make_float2(xr0 + xr1, xi0 + xi1);
}

// ---------------- mode mixing: Y[b,o,m] = sum_i X[b,i,m] * (wre+j*wim)[i,o,m] -------------
__global__ __launch_bounds__(256, 2)
void k_mix(const float2* __restrict__ X, const float* __restrict__ wre,
           const float* __restrict__ wim, float2* __restrict__ Y) {
    int o = blockIdx.x >> 2;   // 0..63
    int bq = blockIdx.x & 3;   // pair of batches
    int m = threadIdx.x;       // mode = ky*16+kx
    int b0 = bq * 2, b1 = bq * 2 + 1;
    float yr0 = 0.f, yi0 = 0.f, yr1 = 0.f, yi1 = 0.f;
    for (int i = 0; i < C; ++i) {
        float wr = wre[(i * C + o) * 256 + m];
        float wi = wim[(i * C + o) * 256 + m];
        float2 x0 = X[(b0 * C + i) * 256 + m];
        float2 x1 = X[(b1 * C + i) * 256 + m];
        yr0 = fmaf(x0.x, wr, fmaf(-x0.y, wi, yr0));
        yi0 = fmaf(x0.x, wi, fmaf(x0.y, wr, yi0));
        yr1 = fmaf(x1.x, wr, fmaf(-x1.y, wi, yr1));
        yi1 = fmaf(x1.x, wi, fmaf(x1.y, wr, yi1));
    }
    Y[(b0 * C + o) * 256 + m] = make_float2(yr0, yi0);
    Y[(b1 * C + o) * 256 + m] = make_float2(yr1, yi1);
}

// ---------------- inverse along y (with 1/(H*W) and Hermitian x2 folded in) ---------------
// G[bc, y, kx] = scale(kx) * sum_ky Y[bc, ky*16+kx] e^{+2pi i ky y/256}
__global__ __launch_bounds__(256, 2)
void k_inv_y(const float2* __restrict__ Y, const float2* __restrict__ tab,
             float2* __restrict__ G) {
    __shared__ float2 sY[256];
    __shared__ float2 st[256];
    int bc = blockIdx.x, t = threadIdx.x;   // t = y
    sY[t] = Y[bc * 256 + t];
    st[t] = tab[t];
    __syncthreads();
    float2 out[M];
#pragma unroll
    for (int kx = 0; kx < M; ++kx) {
        float gr = 0.f, gi = 0.f;
#pragma unroll
        for (int ky = 0; ky < M; ++ky) {
            float2 yv = sY[ky * 16 + kx];
            float2 e = st[(ky * t) & 255];
            gr = fmaf(yv.x, e.x, fmaf(-yv.y, e.y, gr));
            gi = fmaf(yv.x, e.y, fmaf(yv.y, e.x, gi));
        }
        float sc = (kx == 0 ? 1.0f : 2.0f) * (1.0f / 65536.0f);
        out[kx] = make_float2(gr * sc, gi * sc);
    }
    float2* gp = G + (bc * 256 + t) * M;
#pragma unroll
    for (int kx = 0; kx < M; ++kx) gp[kx] = out[kx];
}

// ---------------- fused: inverse along x + conv1x1 + add + relu, in-place on h ------------
// R1: __launch_bounds__(256,2) to kill hp[64] spill. R3: sG LDS stage (8 KB) to kill
// per-o scalar-load stalls. R4: 4 independent accumulator chains per o — the single
// 96-FMA dependent chain stalled ~50% of issue slots at ~2 resident waves/SIMD
// (R3: VALUBusy 38%, dur 186 us vs 41 us issue floor). fp32 FMA reassociation must
// be manual (strict fp).
__global__ __launch_bounds__(256, 2)
void k_final(float* __restrict__ h, const float2* __restrict__ G,
             const float* __restrict__ ww, const float* __restrict__ wb,
             const float2* __restrict__ tab) {
    __shared__ float2 sG[C * M];    // 8 KB, [o][k]
    __shared__ float2 st[256];      // 2 KB
    int by = blockIdx.x;
    int b = by >> 8, y = by & 255;
    int x = threadIdx.x;
    st[x] = tab[x];
    {
        // 64 o-rows x 8 float4 each = 512 float4; threads f=8o..8o+7 fetch one
        // contiguous 128 B row -> fully coalesced.
        const float4* Gf4 = (const float4*)G;
        float4* sGf4 = (float4*)sG;
        int f0 = x;                      // pass 0
        int o0 = f0 >> 3, q0 = f0 & 7;
        sGf4[f0] = Gf4[((size_t)(b * C + o0) * 256 + y) * 8 + q0];
        int f1 = x + 256;                // pass 1
        int o1 = f1 >> 3, q1 = f1 & 7;
        sGf4[f1] = Gf4[((size_t)(b * C + o1) * 256 + y) * 8 + q1];
    }
    __syncthreads();
    float cs[M], sn[M];
#pragma unroll
    for (int k = 0; k < M; ++k) {
        float2 e = st[(k * x) & 255];
        cs[k] = e.x; sn[k] = e.y;
    }
    float hp[C];
    float* hb = h + b * C * HW + y * Wd + x;
#pragma unroll
    for (int i = 0; i < C; ++i) hp[i] = hb[i * HW];
    for (int o = 0; o < C; ++o) {
        const float* wr = ww + o * C;        // uniform -> scalar loads (sL1-hot)
        // 4 independent chains: a0..a3. conv part round-robins i%4; spectral part
        // feeds chains 0 (cos) and 1 (sin).
        float a0 = wb[o], a1 = 0.f, a2 = 0.f, a3 = 0.f;
#pragma unroll
        for (int i = 0; i < C; i += 4) {
            a0 = fmaf(wr[i + 0], hp[i + 0], a0);
            a1 = fmaf(wr[i + 1], hp[i + 1], a1);
            a2 = fmaf(wr[i + 2], hp[i + 2], a2);
            a3 = fmaf(wr[i + 3], hp[i + 3], a3);
        }
        const float2* gp = &sG[o * M];       // uniform LDS -> broadcast, conflict-free
#pragma unroll
        for (int k = 0; k < M; k += 2) {
            float2 g0 = gp[k], g1 = gp[k + 1];
            a0 = fmaf(g0.x, cs[k], a0);
            a1 = fmaf(-g0.y, sn[k], a1);
            a2 = fmaf(g1.x, cs[k + 1], a2);
            a3 = fmaf(-g1.y, sn[k + 1], a3);
        }
        hb[o * HW] = fmaxf((a0 + a1) + (a2 + a3), 0.0f);
    }
}

// ---------------- fused fc1 (relu) + fc2, per pixel ----------------
// R4: same 4-chain ILP split as k_final (was a 64-deep serial FMA chain per m).
__global__ __launch_bounds__(256, 2)
void k_fc12(const float* __restrict__ h, const float* __restrict__ w1,
            const float* __restrict__ b1, const float* __restrict__ w2,
            const float* __restrict__ b2, float* __restrict__ out) {
    int by = blockIdx.x;
    int b = by >> 8, y = by & 255;
    int x = threadIdx.x;
    const float* hb = h + b * C * HW + y * Wd + x;
    float hp[C];
#pragma unroll
    for (int i = 0; i < C; ++i) hp[i] = hb[i * HW];
    float a0 = b2[0], a1 = b2[1], a2 = b2[2];
    for (int m = 0; m < NMLP; ++m) {
        const float* wr = w1 + m * C;
        float c0 = b1[m], c1 = 0.f, c2 = 0.f, c3 = 0.f;
#pragma unroll
        for (int i = 0; i < C; i += 4) {
            c0 = fmaf(wr[i + 0], hp[i + 0], c0);
            c1 = fmaf(wr[i + 1], hp[i + 1], c1);
            c2 = fmaf(wr[i + 2], hp[i + 2], c2);
            c3 = fmaf(wr[i + 3], hp[i + 3], c3);
        }
        float acc = fmaxf((c0 + c1) + (c2 + c3), 0.0f);
        a0 = fmaf(w2[0 * NMLP + m], acc, a0);
        a1 = fmaf(w2[1 * NMLP + m], acc, a1);
        a2 = fmaf(w2[2 * NMLP + m], acc, a2);
    }
    float* ob = out + b * 3 * HW + y * Wd + x;
    ob[0] = a0;
    ob[HW] = a1;
    ob[2 * HW] = a2;
}

extern "C" void kernel_launch(void* const* d_in, const int* in_sizes, int n_in,
                              void* d_out, int out_size, void* d_ws, size_t ws_size,
                              hipStream_t stream) {
    const float* x     = (const float*)d_in[0];
    const float* fc0_w = (const float*)d_in[1];
    const float* fc0_b = (const float*)d_in[2];
    const float* swre  = (const float*)d_in[3];   // [4,64,64,16,16]
    const float* swim  = (const float*)d_in[4];
    const float* ww    = (const float*)d_in[5];   // [4,64,64]
    const float* wb    = (const float*)d_in[6];   // [4,64]
    const float* fc1w  = (const float*)d_in[7];
    const float* fc1b  = (const float*)d_in[8];
    const float* fc2w  = (const float*)d_in[9];
    const float* fc2b  = (const float*)d_in[10];

    float* ws = (float*)d_ws;
    float2* tab = (float2*)ws;                               // 512 floats
    float*  h   = ws + 512;                                  // 33,554,432 floats
    float2* T1  = (float2*)(ws + 512 + 33554432);            // 4,194,304 floats (doubles as G)
    float2* X   = (float2*)(ws + 512 + 33554432 + 4194304);  // 262,144 floats
    float2* Y   = (float2*)(ws + 512 + 33554432 + 4194304 + 262144); // 262,144 floats
    // total ~153 MB of workspace

    k_table<<<dim3(1), dim3(256), 0, stream>>>(tab);
    k_fc0<<<dim3(2048), dim3(256), 0, stream>>>(x, fc0_w, fc0_b, h);

    for (int d = 0; d < NDEPTH; ++d) {
        k_fwd_y<<<dim3(512), dim3(256), 0, stream>>>(h, tab, T1);
        k_fwd_x<<<dim3(512), dim3(256), 0, stream>>>(T1, tab, X);
        k_mix<<<dim3(256), dim3(256), 0, stream>>>(X, swre + (size_t)d * C * C * 256,
                                                   swim + (size_t)d * C * C * 256, Y);
        k_inv_y<<<dim3(512), dim3(256), 0, stream>>>(Y, tab, T1 /* reused as G */);
        k_final<<<dim3(2048), dim3(256), 0, stream>>>(h, T1, ww + d * C * C, wb + d * C, tab);
    }
    k_fc12<<<dim3(2048), dim3(256), 0, stream>>>(h, fc1w, fc1b, fc2w, fc2b, (float*)d_out);
}